// Round 1
// baseline (582.543 us; speedup 1.0000x reference)
//
#include <hip/hip_runtime.h>
#include <math.h>

typedef __bf16 bf16;
typedef __bf16 bf16x4 __attribute__((ext_vector_type(4)));
typedef __bf16 bf16x8 __attribute__((ext_vector_type(8)));
typedef float floatx4 __attribute__((ext_vector_type(4)));

#define MFMA16(a, b, c) __builtin_amdgcn_mfma_f32_16x16x32_bf16(a, b, c, 0, 0, 0)

constexpr int Bc = 4, SQc = 2048, SKVc = 2048, Hc = 16, Dc = 64;

// ---------------------------------------------------------------------------
// Generic 64x64-tile bf16 MFMA GEMM with fused epilogues.
//   MODE 0: C = A(bf16) @ W + bias      -> fp32 out [M][Ntot]
//   MODE 1: C = A(f32) @ W + bias, RoPE, *0.125 -> qh bf16 [b][h][s][d]
//   MODE 2: C = A(f32) @ W + bias; cols<64: RoPE -> k bf16 [b][skv][d]
//                                  cols>=64:      -> vT bf16 [b][d][skv]
// ---------------------------------------------------------------------------
template <typename AT, int MODE>
__global__ __launch_bounds__(256) void gemm_rope(
    const AT* __restrict__ A, const float* __restrict__ W,
    const float* __restrict__ bias, void* __restrict__ out0,
    void* __restrict__ out1, int M, int K, int Ntot) {
  __shared__ bf16 As[64][40];   // [m][k], +8 pad -> 2-way max conflicts
  __shared__ bf16 Bst[64][40];  // [n][k] (transposed), +8 pad

  const int tid = threadIdx.x;
  const int lane = tid & 63, wave = tid >> 6;
  const int m0 = blockIdx.x * 64, n0 = blockIdx.y * 64;

  floatx4 zero4 = {0.f, 0.f, 0.f, 0.f};
  floatx4 acc[4] = {zero4, zero4, zero4, zero4};

  for (int k0 = 0; k0 < K; k0 += 32) {
    __syncthreads();
    // ---- stage A tile (64 x 32) as bf16 ----
    if constexpr (sizeof(AT) == 4) {
      const int r0 = tid >> 3, c4 = (tid & 7) * 4;
#pragma unroll
      for (int hf = 0; hf < 2; hf++) {
        const int row = r0 + 32 * hf;
        const float4 av = *(const float4*)&A[(size_t)(m0 + row) * K + k0 + c4];
        bf16x4 b4 = {(bf16)av.x, (bf16)av.y, (bf16)av.z, (bf16)av.w};
        *(bf16x4*)&As[row][c4] = b4;
      }
    } else {
      const int row = tid >> 2, c8 = (tid & 3) * 8;
      *(bf16x8*)&As[row][c8] = *(const bf16x8*)&A[(size_t)(m0 + row) * K + k0 + c8];
    }
    // ---- stage W tile transposed: Bst[n][k] (32 x 64 source) ----
    {
      const int kk = tid >> 4, n4 = (tid & 15) * 4;
#pragma unroll
      for (int hf = 0; hf < 2; hf++) {
        const int k = kk + 16 * hf;
        const float4 wv = *(const float4*)&W[(size_t)(k0 + k) * Ntot + n0 + n4];
        Bst[n4 + 0][k] = (bf16)wv.x;
        Bst[n4 + 1][k] = (bf16)wv.y;
        Bst[n4 + 2][k] = (bf16)wv.z;
        Bst[n4 + 3][k] = (bf16)wv.w;
      }
    }
    __syncthreads();
    // ---- MFMA: wave w computes rows [16w,16w+16) x cols [0,64) ----
    const bf16x8 af = *(const bf16x8*)&As[16 * wave + (lane & 15)][8 * (lane >> 4)];
#pragma unroll
    for (int t = 0; t < 4; t++) {
      const bf16x8 bfr = *(const bf16x8*)&Bst[16 * t + (lane & 15)][8 * (lane >> 4)];
      acc[t] = MFMA16(af, bfr, acc[t]);
    }
  }

  // ---- epilogue. C/D layout: col = lane&15 (+16t), row = 4*(lane>>4)+reg ----
  const int colq = lane & 15, rq = 4 * (lane >> 4);
#pragma unroll
  for (int t = 0; t < 4; t++) {
    const int col = n0 + 16 * t + colq;
    const float bv = bias[col];
#pragma unroll
    for (int r = 0; r < 4; r++) {
      const int row = m0 + 16 * wave + rq + r;
      float v = acc[t][r] + bv;
      if constexpr (MODE == 0) {
        ((float*)out0)[(size_t)row * Ntot + col] = v;
      } else if constexpr (MODE == 1) {
        const float vp = __shfl_xor(v, 1);  // partner col = col^1 (adjacent lane)
        const int d = col & 63, hh = col >> 6;
        const int pos = row & (SQc - 1), b = row >> 11;
        const float ang = (float)pos * exp2f(-0.375f * (float)(d >> 1));
        float sn, cs;
        sincosf(ang, &sn, &cs);
        const float res = (d & 1) ? (v * cs + vp * sn) : (v * cs - vp * sn);
        ((bf16*)out0)[(((size_t)(b * Hc + hh) * SQc) + pos) * Dc + d] =
            (bf16)(res * 0.125f);  // fold 1/sqrt(D), exact in bf16
      } else {  // MODE 2
        const float vp = __shfl_xor(v, 1);
        const int pos = row & (SKVc - 1), b = row >> 11;
        if (col < 64) {  // uniform per block (n0 is 0 or 64)
          const int d = col;
          const float ang = (float)pos * exp2f(-0.375f * (float)(d >> 1));
          float sn, cs;
          sincosf(ang, &sn, &cs);
          const float res = (d & 1) ? (v * cs + vp * sn) : (v * cs - vp * sn);
          ((bf16*)out0)[((size_t)b * SKVc + pos) * Dc + d] = (bf16)res;
        } else {
          ((bf16*)out1)[((size_t)b * Dc + (col - 64)) * SKVc + pos] = (bf16)v;
        }
      }
    }
  }
}

// ---------------------------------------------------------------------------
// Flash attention: block = (b, h, 64-q-rows). 4 waves x 16 q-rows each.
// qh pre-scaled by 1/sqrt(D). K-tile = 64 keys per iteration.
// ---------------------------------------------------------------------------
__global__ __launch_bounds__(256) void attn_kernel(
    const bf16* __restrict__ qh, const bf16* __restrict__ kk,
    const bf16* __restrict__ vt, bf16* __restrict__ hout) {
  const int blk = blockIdx.x;
  const int qt = blk & 31;
  const int h = (blk >> 5) & 15;
  const int b = blk >> 9;
  const int tid = threadIdx.x, lane = tid & 63, wave = tid >> 6;

  __shared__ bf16 Ks[64][72];       // [key][d], pad->2-way max
  __shared__ bf16 Vs[64][72];       // [d][key] (from vT)
  __shared__ bf16 Ps[4][16][72];    // per-wave P relayout buffer

  const int q0 = qt * 64 + wave * 16;
  // A-frag (m = lane&15, k = 8*(lane>>4)+j): 16B loads from qh rows
  const bf16* qptr =
      qh + ((size_t)((b * Hc + h) * SQc) + q0 + (lane & 15)) * Dc + 8 * (lane >> 4);
  const bf16x8 aq0 = *(const bf16x8*)qptr;
  const bf16x8 aq1 = *(const bf16x8*)(qptr + 32);

  floatx4 zero4 = {0.f, 0.f, 0.f, 0.f};
  floatx4 accO[4] = {zero4, zero4, zero4, zero4};
  float mrow[4] = {-INFINITY, -INFINITY, -INFINITY, -INFINITY};
  float lrow[4] = {0.f, 0.f, 0.f, 0.f};

  const bf16* kbase = kk + (size_t)b * SKVc * Dc;
  const bf16* vbase = vt + (size_t)b * Dc * SKVc;
  const int sr0 = tid >> 3, sc = (tid & 7) * 8;

  for (int kt = 0; kt < SKVc; kt += 64) {
    __syncthreads();
#pragma unroll
    for (int hf = 0; hf < 2; hf++) {
      const int row = sr0 + 32 * hf;
      *(bf16x8*)&Ks[row][sc] = *(const bf16x8*)(kbase + (size_t)(kt + row) * Dc + sc);
      *(bf16x8*)&Vs[row][sc] = *(const bf16x8*)(vbase + (size_t)row * SKVc + kt + sc);
    }
    __syncthreads();

    // ---- S = Q K^T (16 x 64 per wave) ----
    floatx4 s[4] = {zero4, zero4, zero4, zero4};
#pragma unroll
    for (int t = 0; t < 4; t++) {
      const bf16x8 bk0 = *(const bf16x8*)&Ks[16 * t + (lane & 15)][8 * (lane >> 4)];
      const bf16x8 bk1 = *(const bf16x8*)&Ks[16 * t + (lane & 15)][32 + 8 * (lane >> 4)];
      s[t] = MFMA16(aq0, bk0, s[t]);
      s[t] = MFMA16(aq1, bk1, s[t]);
    }

    // ---- online softmax (row r lives in lanes sharing lane>>4) ----
#pragma unroll
    for (int r = 0; r < 4; r++) {
      float mx = fmaxf(fmaxf(s[0][r], s[1][r]), fmaxf(s[2][r], s[3][r]));
#pragma unroll
      for (int off = 1; off < 16; off <<= 1) mx = fmaxf(mx, __shfl_xor(mx, off));
      const float mnew = fmaxf(mrow[r], mx);
      const float al = __expf(mrow[r] - mnew);
      float rs = 0.f;
#pragma unroll
      for (int t = 0; t < 4; t++) {
        const float p = __expf(s[t][r] - mnew);
        s[t][r] = p;
        rs += p;
      }
#pragma unroll
      for (int off = 1; off < 16; off <<= 1) rs += __shfl_xor(rs, off);
      lrow[r] = lrow[r] * al + rs;
      mrow[r] = mnew;
#pragma unroll
      for (int t = 0; t < 4; t++) accO[t][r] *= al;
    }

    // ---- P: C-layout -> LDS -> A-layout ----
    const int pr = 4 * (lane >> 4);
#pragma unroll
    for (int t = 0; t < 4; t++)
#pragma unroll
      for (int r = 0; r < 4; r++)
        Ps[wave][pr + r][16 * t + (lane & 15)] = (bf16)s[t][r];
    __syncthreads();

    const bf16x8 pa0 = *(const bf16x8*)&Ps[wave][lane & 15][8 * (lane >> 4)];
    const bf16x8 pa1 = *(const bf16x8*)&Ps[wave][lane & 15][32 + 8 * (lane >> 4)];
#pragma unroll
    for (int t = 0; t < 4; t++) {
      const bf16x8 bv0 = *(const bf16x8*)&Vs[16 * t + (lane & 15)][8 * (lane >> 4)];
      const bf16x8 bv1 = *(const bf16x8*)&Vs[16 * t + (lane & 15)][32 + 8 * (lane >> 4)];
      accO[t] = MFMA16(pa0, bv0, accO[t]);
      accO[t] = MFMA16(pa1, bv1, accO[t]);
    }
  }

  // ---- normalize and store h[b][s][h*64+d] ----
  const int rq = 4 * (lane >> 4);
#pragma unroll
  for (int t = 0; t < 4; t++) {
#pragma unroll
    for (int r = 0; r < 4; r++) {
      const float o = accO[t][r] / lrow[r];
      const int qrow = q0 + rq + r;
      const int d = 16 * t + (lane & 15);
      hout[((size_t)(b * SQc + qrow)) * (Hc * Dc) + h * Dc + d] = (bf16)o;
    }
  }
}

// ---------------------------------------------------------------------------
extern "C" void kernel_launch(void* const* d_in, const int* in_sizes, int n_in,
                              void* d_out, int out_size, void* d_ws, size_t ws_size,
                              hipStream_t stream) {
  const float* q = (const float*)d_in[0];
  const float* kv = (const float*)d_in[1];
  const float* Wq = (const float*)d_in[2];
  const float* bq = (const float*)d_in[3];
  const float* Wkv = (const float*)d_in[4];
  const float* bkv = (const float*)d_in[5];
  const float* Wo = (const float*)d_in[6];
  const float* bo = (const float*)d_in[7];

  char* ws = (char*)d_ws;
  bf16* qh = (bf16*)ws;                              // 4*16*2048*64 *2B = 16 MiB
  bf16* kk = (bf16*)(ws + (size_t)16777216);         // 4*2048*64 *2B = 1 MiB
  bf16* vt = (bf16*)(ws + (size_t)16777216 + 1048576);
  bf16* hh = (bf16*)(ws + (size_t)16777216 + 2097152);  // 16 MiB

  // Q projection + RoPE + scale -> qh[b][h][s][d]
  gemm_rope<float, 1><<<dim3(128, 16), 256, 0, stream>>>(
      q, Wq, bq, (void*)qh, nullptr, Bc * SQc, 1024, Hc * Dc);
  // KV projection (+ RoPE on k) -> k[b][skv][d], vT[b][d][skv]
  gemm_rope<float, 2><<<dim3(128, 2), 256, 0, stream>>>(
      kv, Wkv, bkv, (void*)kk, (void*)vt, Bc * SKVc, 1024, 2 * Dc);
  // Flash attention -> h[b][s][h*64+d]
  attn_kernel<<<Bc * Hc * (SQc / 64), 256, 0, stream>>>(qh, kk, vt, hh);
  // Output projection -> fp32 d_out
  gemm_rope<bf16, 0><<<dim3(128, 16), 256, 0, stream>>>(
      hh, Wo, bo, d_out, nullptr, Bc * SQc, Hc * Dc, 1024);
}